// Round 8
// baseline (124.943 us; speedup 1.0000x reference)
//
#include <hip/hip_runtime.h>
#include <hip/hip_fp16.h>

#define TAU 0.07f
#define MARGIN 0.2f
#define NSPEC 64
#define BB 8192
#define DD 256

// ---------------- ws layout (bytes) ----------------
// zeroed-by-k1-block0 region: [0, 107072)
//   0      float scalars[8] [2]=n_valid [3]=n_valid_i [4]=doneCnt(int,k67)
//   64     buckets: 64 x 128B lines; line b: {float info, float tri} at b*128
//   8256   int   counts[64]
//   8512   int   offsets[64]
//   8768   float lseRow[B]      (exp-sum, rows of same-species block)
//   41536  float lseCol[B]      (exp-sum, cols)
//   74304  float rawRow[B]      (raw sim row-sum incl diag, f16-MFMA precision)
// unzeroed:
//   107072 int   posg[B]        (row -> grouped index g)
//   139840 int   memberList[B]  (g -> row)
//   172608 float Tpart[128*256] (plain-store partials, no zero needed)
//   303680 float T[256]
#define WS_SCALARS   0
#define WS_BUCKET    64
#define WS_COUNTS    8256
#define WS_OFFSETS   8512
#define WS_LSEROW    8768
#define WS_LSECOL    41536
#define WS_RAWROW    74304
#define WS_ZERO_BYTES 107072   // 6692 float4
#define WS_POSG      107072
#define WS_MEMBER    139840
#define WS_TPART     172608
#define WS_T         303680

typedef _Float16 half8 __attribute__((ext_vector_type(8)));
typedef float float4v __attribute__((ext_vector_type(4)));
typedef unsigned int uint4v __attribute__((ext_vector_type(4)));

#define NB5 512          // MFMA blocks (species x 4 rt x 2 ct); +1 T-reduce block
#define NTP 128          // Tpart blocks fused into k1

__device__ __forceinline__ uint4v pack8(float4 a, float4 b) {
  half8 h;
  h[0] = (_Float16)a.x; h[1] = (_Float16)a.y; h[2] = (_Float16)a.z; h[3] = (_Float16)a.w;
  h[4] = (_Float16)b.x; h[5] = (_Float16)b.y; h[6] = (_Float16)b.z; h[7] = (_Float16)b.w;
  return __builtin_bit_cast(uint4v, h);
}

// ---- k1: block 0: zero + counts + scan + scatter + posg + valid-counts.
//          blocks 1..NTP: Tpart[b][d] = sum of 64 tx rows (plain stores). ----
__global__ void k1_all(const int* __restrict__ ids, const float* __restrict__ tx,
                       char* ws, int* counts_g, int* offsets_g,
                       int* memberList, int* posg, float* Tpart, float* scalars) {
  int tid = threadIdx.x;
  if (blockIdx.x > 0) {
    __shared__ float part[4][256];
    int b = blockIdx.x - 1;          // 0..127
    int d = tid & 255;
    int rq = tid >> 8;               // 0..3
    int r0 = b * 64 + rq * 16;
    float acc = 0.f;
    #pragma unroll 4
    for (int k = 0; k < 16; ++k) acc += tx[(r0 + k) * DD + d];
    part[rq][d] = acc;
    __syncthreads();
    if (tid < 256)
      Tpart[b * 256 + tid] = part[0][tid] + part[1][tid] + part[2][tid] + part[3][tid];
    return;
  }
  __shared__ int cnt[NSPEC];
  __shared__ int off[NSPEC];
  float4* z = (float4*)ws;
  float4 z4 = make_float4(0.f, 0.f, 0.f, 0.f);
  for (int u = tid; u < WS_ZERO_BYTES / 16; u += 1024) z[u] = z4;
  if (tid < NSPEC) cnt[tid] = 0;
  __syncthreads();
  int myS[8], myP[8];
  #pragma unroll
  for (int r = 0; r < 8; ++r) {
    int i = r * 1024 + tid;
    int s = ids[i];
    myS[r] = s;
    myP[r] = atomicAdd(&cnt[s], 1);
  }
  __syncthreads();
  if (tid < NSPEC) {  // exactly wave 0
    int o = 0;
    for (int t = 0; t < NSPEC; ++t) o += (t < tid) ? cnt[t] : 0;
    off[tid] = o;
    offsets_g[tid] = o;
    int c = cnt[tid];
    counts_g[tid] = c;
    unsigned long long bv = __ballot(c >= 2);
    float nvi = (c >= 2 && c <= BB - 1) ? (float)c : 0.f;
    for (int o2 = 1; o2 < 64; o2 <<= 1) nvi += __shfl_xor(nvi, o2);
    if (tid == 0) {
      scalars[2] = (float)__popcll(bv);
      scalars[3] = nvi;
    }
  }
  __syncthreads();
  #pragma unroll
  for (int r = 0; r < 8; ++r) {
    int i = r * 1024 + tid;
    int g = off[myS[r]] + myP[r];
    memberList[g] = i;
    posg[i] = g;
  }
}

// ---- k5: blocks [0,NB5): per-species MFMA exp-sum + raw row-sum.
//          block NB5: reduce Tpart -> T. ----
__global__ void k5_lse(const float* __restrict__ sp, const float* __restrict__ tx,
                       const int* __restrict__ counts, const int* __restrict__ offsets,
                       const int* __restrict__ memberList,
                       const float* __restrict__ Tpart, float* T,
                       float* lseRow, float* lseCol, float* rawRow) {
  __shared__ uint4v lds5[1536];  // A: [0,512) ; B: [512,1536)  (24 KB)
  int tid = threadIdx.x;

  if (blockIdx.x == NB5) {
    float acc = 0.f;
    for (int b = 0; b < NTP; ++b) acc += Tpart[b * 256 + tid];
    T[tid] = acc;
    return;
  }

  int s = blockIdx.x >> 3;
  int sub = blockIdx.x & 7;
  int rt0 = sub >> 1;   // stride 4
  int ct0 = sub & 1;    // stride 2
  int m = counts[s];
  int g0 = offsets[s];
  int lane = tid & 63, wv = tid >> 6;
  int quad = lane >> 4, cl = lane & 15;

  for (int rt = rt0; rt * 64 < m; rt += 4) {
    for (int ct = ct0; ct * 128 < m; ct += 2) {
      float4v acc[8];
      #pragma unroll
      for (int cf = 0; cf < 8; ++cf) acc[cf] = (float4v){0.f, 0.f, 0.f, 0.f};

      for (int kc = 0; kc < 4; ++kc) {
        __syncthreads();
        #pragma unroll
        for (int p = 0; p < 6; ++p) {
          int u = p * 256 + tid;
          int isB = u >= 512;
          int v = isB ? (u - 512) : u;
          int row = v >> 3;            // A: 0..63 ; B: 0..127
          int subu = v & 7;
          int ksl = subu >> 2, q = subu & 3;
          int d0 = kc * 64 + ksl * 32 + q * 8;
          int idx = isB ? (ct * 128 + row) : (rt * 64 + row);
          uint4v val = (uint4v){0u, 0u, 0u, 0u};
          if (idx < m) {
            const float* src = (isB ? tx : sp) + memberList[g0 + idx] * DD + d0;
            float4 f0 = *reinterpret_cast<const float4*>(src);
            float4 f1 = *reinterpret_cast<const float4*>(src + 4);
            val = pack8(f0, f1);
          }
          int qs = q ^ ((row >> 1) & 3);  // bank swizzle
          int dst = isB ? (512 + (ksl * 128 + row) * 4 + qs)
                        : ((ksl * 64 + row) * 4 + qs);
          lds5[dst] = val;
        }
        __syncthreads();
        #pragma unroll
        for (int ksl = 0; ksl < 2; ++ksl) {
          int ar = wv * 16 + cl;
          half8 a = __builtin_bit_cast(half8,
              lds5[(ksl * 64 + ar) * 4 + (quad ^ ((ar >> 1) & 3))]);
          #pragma unroll
          for (int cf = 0; cf < 8; ++cf) {
            int br = cf * 16 + cl;
            half8 b = __builtin_bit_cast(half8,
                lds5[512 + (ksl * 128 + br) * 4 + (quad ^ ((br >> 1) & 3))]);
            acc[cf] = __builtin_amdgcn_mfma_f32_16x16x32_f16(a, b, acc[cf], 0, 0, 0);
          }
        }
      }

      // epilogue: masked exp + raw sums, row/col reductions
      int riBase = rt * 64 + wv * 16 + quad * 4;  // + reg
      float rowAcc[4] = {0.f, 0.f, 0.f, 0.f};
      float rawAcc[4] = {0.f, 0.f, 0.f, 0.f};
      #pragma unroll
      for (int cf = 0; cf < 8; ++cf) {
        int ci = ct * 128 + cf * 16 + cl;
        bool cv = ci < m;
        float colAcc = 0.f;
        #pragma unroll
        for (int reg = 0; reg < 4; ++reg) {
          bool rv = (riBase + reg) < m;
          bool on = rv && cv;
          float sv = on ? acc[cf][reg] : 0.f;
          float e = on ? __expf(sv * (1.f / TAU)) : 0.f;
          rowAcc[reg] += e;
          rawAcc[reg] += sv;
          colAcc += e;
        }
        colAcc += __shfl_xor(colAcc, 16);
        colAcc += __shfl_xor(colAcc, 32);
        if (quad == 0 && cv) atomicAdd(&lseCol[g0 + ci], colAcc);
      }
      #pragma unroll
      for (int reg = 0; reg < 4; ++reg) {
        float v = rowAcc[reg];
        float w = rawAcc[reg];
        v += __shfl_xor(v, 1);  w += __shfl_xor(w, 1);
        v += __shfl_xor(v, 2);  w += __shfl_xor(w, 2);
        v += __shfl_xor(v, 4);  w += __shfl_xor(w, 4);
        v += __shfl_xor(v, 8);  w += __shfl_xor(w, 8);
        if (cl == 0 && (riBase + reg) < m) {
          atomicAdd(&lseRow[g0 + riBase + reg], v);
          atomicAdd(&rawRow[g0 + riBase + reg], w);
        }
      }
    }
  }
}

// ---- k67: full row pass (diag, dT, tri, info) + bucketed scalar reduction
//      + arrival-counter finalize (s_waitcnt, NO threadfence). ----
__global__ void k67_info(const float* __restrict__ sp, const float* __restrict__ tx,
                         const int* __restrict__ ids, const int* __restrict__ counts,
                         const int* __restrict__ posg, const float* __restrict__ T,
                         const float* __restrict__ lseRow, const float* __restrict__ lseCol,
                         const float* __restrict__ rawRow, char* ws, float* scalars,
                         float* out) {
  __shared__ float red[8];  // [0..3]=info per wave, [4..7]=tri per wave
  __shared__ int isLast;
  int tid = threadIdx.x;
  int wv = tid >> 6, lane = tid & 63;
  int i = blockIdx.x * 4 + wv;

  float4 a = *reinterpret_cast<const float4*>(sp + i * DD + lane * 4);
  float4 b = *reinterpret_cast<const float4*>(tx + i * DD + lane * 4);
  float4 tv = *reinterpret_cast<const float4*>(T + lane * 4);
  float dDiag = a.x * b.x + a.y * b.y + a.z * b.z + a.w * b.w;
  float dT    = a.x * tv.x + a.y * tv.y + a.z * tv.z + a.w * tv.w;
  #pragma unroll
  for (int o = 1; o < 64; o <<= 1) {
    dDiag += __shfl_xor(dDiag, o);
    dT    += __shfl_xor(dT, o);
  }
  if (lane == 0) {
    int s = ids[i];
    int m = counts[s];
    int g = posg[i];
    float rr = rawRow[g];
    float info = 0.f;
    if (m >= 2) {
      info = (__logf(lseRow[g]) + __logf(lseCol[g]) - 2.f * dDiag * (1.f / TAU)) /
             (2.f * (float)m);
    }
    float posMean = (rr - dDiag) / fmaxf((float)(m - 1), 1.f);
    float negMean = (dT - rr) / fmaxf((float)(BB - m), 1.f);
    float t = fmaxf(negMean - posMean + MARGIN, 0.f);
    float tri = (m >= 2 && m <= BB - 1) ? t : 0.f;
    red[wv] = info;
    red[4 + wv] = tri;
  }
  __syncthreads();
  if (tid == 0) {
    float* bucket = (float*)(ws + WS_BUCKET + (blockIdx.x & 63) * 128);
    atomicAdd(&bucket[0], red[0] + red[1] + red[2] + red[3]);
    atomicAdd(&bucket[1], red[4] + red[5] + red[6] + red[7]);
    __builtin_amdgcn_s_waitcnt(0);  // bucket atomics at coherence point
    int old = atomicAdd((int*)&scalars[4], 1);
    isLast = (old == (int)gridDim.x - 1) ? 1 : 0;
  }
  __syncthreads();
  if (isLast && tid < 64) {
    float* bucket = (float*)(ws + WS_BUCKET + tid * 128);
    float inf = atomicAdd(&bucket[0], 0.f);  // coherent load
    float trs = atomicAdd(&bucket[1], 0.f);
    #pragma unroll
    for (int o = 1; o < 64; o <<= 1) {
      inf += __shfl_xor(inf, o);
      trs += __shfl_xor(trs, o);
    }
    if (tid == 0)
      out[0] = inf / fmaxf(scalars[2], 1.f) + trs / fmaxf(scalars[3], 1.f);
  }
}

extern "C" void kernel_launch(void* const* d_in, const int* in_sizes, int n_in,
                              void* d_out, int out_size, void* d_ws, size_t ws_size,
                              hipStream_t stream) {
  const float* sp = (const float*)d_in[0];
  const float* tx = (const float*)d_in[1];
  const int* ids = (const int*)d_in[2];
  float* out = (float*)d_out;

  char* ws = (char*)d_ws;
  float* scalars = (float*)(ws + WS_SCALARS);
  int* counts = (int*)(ws + WS_COUNTS);
  int* offsets = (int*)(ws + WS_OFFSETS);
  float* lseRow = (float*)(ws + WS_LSEROW);
  float* lseCol = (float*)(ws + WS_LSECOL);
  float* rawRow = (float*)(ws + WS_RAWROW);
  int* posg = (int*)(ws + WS_POSG);
  int* memberList = (int*)(ws + WS_MEMBER);
  float* Tpart = (float*)(ws + WS_TPART);
  float* T = (float*)(ws + WS_T);

  k1_all<<<1 + NTP, 1024, 0, stream>>>(ids, tx, ws, counts, offsets, memberList,
                                       posg, Tpart, scalars);
  k5_lse<<<NB5 + 1, 256, 0, stream>>>(sp, tx, counts, offsets, memberList,
                                      Tpart, T, lseRow, lseCol, rawRow);
  k67_info<<<BB / 4, 256, 0, stream>>>(sp, tx, ids, counts, posg, T, lseRow, lseCol,
                                       rawRow, ws, scalars, out);
}